// Round 6
// baseline (3995.827 us; speedup 1.0000x reference)
//
#include <hip/hip_runtime.h>
#include <stdint.h>

typedef __attribute__((ext_vector_type(8))) short short8v;
typedef __attribute__((ext_vector_type(4))) short short4v;
typedef __attribute__((ext_vector_type(4))) float float4v;

__device__ __forceinline__ float bf2f(short u) {
  union { unsigned int i; float f; } v;
  v.i = ((unsigned int)(unsigned short)u) << 16;
  return v.f;
}
__device__ __forceinline__ short f2bf(float f) {
  union { float f; unsigned int i; } v; v.f = f;
  unsigned int x = v.i;
  unsigned int r = (x + 0x7fffu + ((x >> 16) & 1u)) >> 16;
  return (short)r;
}
__device__ __forceinline__ float hsigf(float x) {
  return fminf(fmaxf(fmaf(x, 0.2f, 0.5f), 0.0f), 1.0f);
}
__device__ __forceinline__ float tanhf_fast(float x) {
  float e = __expf(2.0f * x);
  return 1.0f - __fdividef(2.0f, e + 1.0f);
}
__device__ __forceinline__ void gload_lds16(const void* g, void* l) {
  __builtin_amdgcn_global_load_lds((const __attribute__((address_space(1))) void*)g,
                                   (__attribute__((address_space(3))) void*)l, 16, 0, 0);
}
// Device-coherent 16B load: bypass the XCD-private L2 (sc0 sc1), coherent at LLC.
__device__ __forceinline__ short8v gload16_cc(const short* p) {
  short8v r;
  asm volatile("global_load_dwordx4 %0, %1, off sc0 sc1" : "=v"(r) : "v"(p));
  return r;
}
// Force a loaded value to be materialized in VGPRs now (kills load-sinking).
__device__ __forceinline__ void pinv(short8v& v) { asm volatile("" : "+v"(v)); }

// ---------------------------------------------------------------------------
// prep_misc: convert weights to bf16 work buffers (flat copies; WHH1 K-padded)
// ---------------------------------------------------------------------------
__global__ __launch_bounds__(256)
void prep_misc(const float* __restrict__ wih0f, const float* __restrict__ wih0b,
               const float* __restrict__ whh0f, const float* __restrict__ whh0b,
               const float* __restrict__ wih2f, const float* __restrict__ wih2b,
               const float* __restrict__ whh2f, const float* __restrict__ whh2b,
               const float* __restrict__ whh1f, const float* __restrict__ whh1b,
               const float* __restrict__ b0f, const float* __restrict__ b0b,
               const float* __restrict__ b2f, const float* __restrict__ b2b,
               short* __restrict__ WG0, short* __restrict__ WG2,
               short* __restrict__ WHH0, short* __restrict__ WHH1, short* __restrict__ WHH2,
               float* __restrict__ B0, float* __restrict__ B2) {
  int i = blockIdx.x * 256 + threadIdx.x;
  if (i < 663552) { WG0[i] = f2bf(i < 331776 ? wih0f[i] : wih0b[i - 331776]); return; }
  i -= 663552;
  if (i < 221184) { WG2[i] = f2bf(i < 110592 ? wih2f[i] : wih2b[i - 110592]); return; }
  i -= 221184;
  if (i < 663552) { WHH0[i] = f2bf(i < 331776 ? whh0f[i] : whh0b[i - 331776]); return; }
  i -= 663552;
  if (i < 184320) {
    int n = i / 160, k = i - n * 160;
    float v = 0.0f;
    if (k < 144) v = (n < 576) ? whh1f[n * 144 + k] : whh1b[(n - 576) * 144 + k];
    WHH1[i] = f2bf(v); return;
  }
  i -= 184320;
  if (i < 73728) { WHH2[i] = f2bf(i < 36864 ? whh2f[i] : whh2b[i - 36864]); return; }
  i -= 73728;
  if (i < 2304) { B0[i] = (i < 1152) ? b0f[i] : b0b[i - 1152]; return; }
  i -= 2304;
  if (i < 768) { B2[i] = (i < 384) ? b2f[i] : b2b[i - 384]; return; }
}

// ---------------------------------------------------------------------------
// prep_bn: fold BatchNorm into layer-1 input weights/bias
// ---------------------------------------------------------------------------
__global__ __launch_bounds__(64)
void prep_bn(const float* __restrict__ w1f, const float* __restrict__ w1b,
             const float* __restrict__ bf1, const float* __restrict__ bb1,
             const float* __restrict__ gamma, const float* __restrict__ beta,
             const float* __restrict__ mean, const float* __restrict__ var,
             short* __restrict__ WG1, float* __restrict__ B1) {
  int n = blockIdx.x;
  int lane = threadIdx.x;
  const float* wrow = (n < 576) ? (w1f + (long)n * 576) : (w1b + (long)(n - 576) * 576);
  float bsrc = (n < 576) ? bf1[n] : bb1[n - 576];
  float part = 0.0f;
  for (int k = lane; k < 576; k += 64) {
    float sc = gamma[k] * rsqrtf(var[k] + 1e-3f);
    float off = beta[k] - mean[k] * sc;
    float w = wrow[k];
    WG1[(long)n * 576 + k] = f2bf(w * sc);
    part += w * off;
  }
#pragma unroll
  for (int m = 32; m >= 1; m >>= 1) part += __shfl_xor(part, m, 64);
  if (lane == 0) B1[n] = bsrc + part;
}

// ---------------------------------------------------------------------------
// embed
// ---------------------------------------------------------------------------
__global__ __launch_bounds__(256)
void embed_k(const int* __restrict__ x, const float* __restrict__ emb, short* __restrict__ A0) {
  int p0 = blockIdx.x * 16;
  for (int j = threadIdx.x; j < 16 * 72; j += 256) {
    int p = p0 + j / 72;
    int cc = j - (j / 72) * 72;
    int idx = x[p];
    float4v v = *(const float4v*)(emb + (long)idx * 288 + cc * 4);
    short4v s;
    s[0] = f2bf(v[0]); s[1] = f2bf(v[1]); s[2] = f2bf(v[2]); s[3] = f2bf(v[3]);
    *(short4v*)(A0 + (long)p * 288 + cc * 4) = s;
  }
}

// ---------------------------------------------------------------------------
// gemm_xg (unchanged)
// ---------------------------------------------------------------------------
__global__ __launch_bounds__(256)
void gemm_xg(const short* __restrict__ A, const short* __restrict__ W,
             const float* __restrict__ bias, short* __restrict__ C,
             int M, int N, int K, int H4, int H) {
  __shared__ short As[128 * 32];
  __shared__ short Bs[128 * 32];
  const int nbn = N >> 7;
  const int bm = blockIdx.x / nbn;
  const int bn = blockIdx.x - bm * nbn;
  const long m0 = (long)bm << 7;
  const int n0 = bn << 7;
  const int tid = threadIdx.x;
  const int lane = tid & 63, wv = tid >> 6;
  const int wr = wv >> 1, wc = wv & 1;
  const int l15 = lane & 15, l4 = lane >> 4;

  float4v acc[4][4];
#pragma unroll
  for (int j = 0; j < 4; ++j) {
    float bvj = bias[n0 + wc * 64 + j * 16 + l15];
#pragma unroll
    for (int i = 0; i < 4; ++i) acc[i][j] = float4v{bvj, bvj, bvj, bvj};
  }

  for (int kt = 0; kt < K; kt += 32) {
#pragma unroll
    for (int c = 0; c < 2; ++c) {
      int ci = wv * 128 + c * 64 + lane;
      int row = ci >> 2, slot = ci & 3;
      int k8 = slot ^ (row & 3);
      gload_lds16(A + (m0 + row) * K + kt + k8 * 8, &As[ci * 8]);
      gload_lds16(W + (long)(n0 + row) * K + kt + k8 * 8, &Bs[ci * 8]);
    }
    __syncthreads();
    short8v af[4], bf[4];
#pragma unroll
    for (int i = 0; i < 4; ++i) {
      int row = wr * 64 + i * 16 + l15;
      af[i] = *(const short8v*)&As[row * 32 + ((l4 ^ (row & 3)) * 8)];
    }
#pragma unroll
    for (int j = 0; j < 4; ++j) {
      int row = wc * 64 + j * 16 + l15;
      bf[j] = *(const short8v*)&Bs[row * 32 + ((l4 ^ (row & 3)) * 8)];
    }
#pragma unroll
    for (int i = 0; i < 4; ++i)
#pragma unroll
      for (int j = 0; j < 4; ++j)
        acc[i][j] = __builtin_amdgcn_mfma_f32_16x16x32_bf16(af[i], bf[j], acc[i][j], 0, 0, 0);
    __syncthreads();
  }

#pragma unroll
  for (int j = 0; j < 4; ++j) {
    int n = n0 + wc * 64 + j * 16 + l15;
    int dir = n / H4;
    int rem = n - dir * H4;
    int q = rem / H;
    int u = rem - q * H;
    long np = (long)dir * H4 + u * 4 + q;
#pragma unroll
    for (int i = 0; i < 4; ++i) {
#pragma unroll
      for (int r = 0; r < 4; ++r) {
        long row = m0 + wr * 64 + i * 16 + l4 * 4 + r;
        C[row * N + np] = f2bf(acc[i][j][r]);
      }
    }
  }
}

// ---------------------------------------------------------------------------
// lstm_recX (L0): cross-WG unit-split recurrence. waves_per_eu(1,1) forces the
// scheduler's occupancy target to 1 wave/SIMD -> 512-VGPR pressure limit ->
// weight loads stay hoisted+pinned (truly register-resident). h exchanged via
// LLC (agent atomic stores / sc0sc1 loads); per-WG flag handshake.
// ---------------------------------------------------------------------------
template<int H, int NK, int NU>
__global__ __launch_bounds__(256)
__attribute__((amdgpu_waves_per_eu(1, 1)))
void lstm_recX(const short* __restrict__ xg, int ldxg,
               const short* __restrict__ whh,
               short* __restrict__ out, int ldo,
               int* __restrict__ fl) {
  constexpr int KPAD = NK * 32;
  const int dir = blockIdx.x & 1;
  const int us = blockIdx.x >> 1;
  const int tid = threadIdx.x;
  const int lane = tid & 63;
  const int mt = tid >> 6;
  const int l15 = lane & 15, l4 = lane >> 4;
  int* fl_d = fl + dir * 512 * 32;
  const short* whh_d = whh + (long)dir * (4 * H) * KPAD;
  const int xoff = dir * 4 * H;
  const int ooff = dir * H;
  const int u = us * 16 + l15;

  short8v bw[4][NK];
#pragma unroll
  for (int q = 0; q < 4; ++q)
#pragma unroll
    for (int kk = 0; kk < NK; ++kk) {
      bw[q][kk] = *(const short8v*)(whh_d + (long)(q * H + u) * KPAD + kk * 32 + l4 * 8);
      pinv(bw[q][kk]);
    }

  float cst[4] = {0.0f, 0.0f, 0.0f, 0.0f};
  const int flidx = (lane < NU) ? lane : 0;

  for (int t = 0; t < 512; ++t) {
    const int te = dir ? (511 - t) : t;

    short4v x4[4];
#pragma unroll
    for (int r = 0; r < 4; ++r) {
      const long b_ = mt * 16 + l4 * 4 + r;
      x4[r] = *(const short4v*)(xg + (b_ * 512 + te) * ldxg + xoff + u * 4);
    }

    float4v a0 = {0, 0, 0, 0}, a1 = {0, 0, 0, 0}, a2 = {0, 0, 0, 0}, a3 = {0, 0, 0, 0};
    if (t > 0) {
      const int tp = dir ? (te + 1) : (te - 1);
      int* fb = fl_d + (t - 1) * 32 + flidx;
      while (!__all(__hip_atomic_load(fb, __ATOMIC_RELAXED, __HIP_MEMORY_SCOPE_AGENT) != 0)) {}
      __builtin_amdgcn_sched_barrier(0);
      const short* hbase = out + ((long)(mt * 16 + l15) * 512 + tp) * ldo + ooff + l4 * 8;
      short8v a[NK];
#pragma unroll
      for (int kk = 0; kk < NK; ++kk) a[kk] = gload16_cc(hbase + kk * 32);
      asm volatile("s_waitcnt vmcnt(0)" ::: "memory");
      __builtin_amdgcn_sched_barrier(0);
#pragma unroll
      for (int kk = 0; kk < NK; ++kk) {
        a0 = __builtin_amdgcn_mfma_f32_16x16x32_bf16(a[kk], bw[0][kk], a0, 0, 0, 0);
        a1 = __builtin_amdgcn_mfma_f32_16x16x32_bf16(a[kk], bw[1][kk], a1, 0, 0, 0);
        a2 = __builtin_amdgcn_mfma_f32_16x16x32_bf16(a[kk], bw[2][kk], a2, 0, 0, 0);
        a3 = __builtin_amdgcn_mfma_f32_16x16x32_bf16(a[kk], bw[3][kk], a3, 0, 0, 0);
      }
    }

#pragma unroll
    for (int r = 0; r < 4; ++r) {
      const long b_ = mt * 16 + l4 * 4 + r;
      const long orow = (b_ * 512 + te) * ldo;
      float gi_ = a0[r] + bf2f(x4[r][0]);
      float gf_ = a1[r] + bf2f(x4[r][1]);
      float gg_ = a2[r] + bf2f(x4[r][2]);
      float go_ = a3[r] + bf2f(x4[r][3]);
      float iv = hsigf(gi_), fv = hsigf(gf_), gv = tanhf_fast(gg_), ov = hsigf(go_);
      float cn = fv * cst[r] + iv * gv;
      cst[r] = cn;
      __hip_atomic_store(out + orow + ooff + u, f2bf(ov * tanhf_fast(cn)),
                         __ATOMIC_RELAXED, __HIP_MEMORY_SCOPE_AGENT);
    }

    asm volatile("s_waitcnt vmcnt(0)" ::: "memory");
    __syncthreads();  // all 4 waves drained before this WG's flag
    if (tid == 0)
      __hip_atomic_store(fl_d + t * 32 + us, 1, __ATOMIC_RELAXED, __HIP_MEMORY_SCOPE_AGENT);
  }
}

// ---------------------------------------------------------------------------
// lstm_loc (L1/L2): fully WG-local recurrence. WG = (dir, 16-batch-group);
// grid = 8. 4 waves; wave wv owns unit groups min(wv+4j, NG-1), j<NGW
// (clamped duplicates compute identical values -> benign same-value LDS
// races). waves_per_eu(1,1) -> weights register-resident. h in LDS, one raw
// barrier per step. Zero cross-WG communication.
// ---------------------------------------------------------------------------
template<int H, int NK, int NG, int NGW>
__global__ __launch_bounds__(256)
__attribute__((amdgpu_waves_per_eu(1, 1)))
void lstm_loc(const short* __restrict__ xg, int ldxg,
              const short* __restrict__ whh,
              short* __restrict__ out, int ldo) {
  constexpr int KPAD = NK * 32;
  constexpr int HP = KPAD + 8;
  __shared__ __align__(16) short hbuf[2][16][HP];
  const int dir = blockIdx.x & 1;
  const int bg = blockIdx.x >> 1;
  const int b0 = bg * 16;
  const int tid = threadIdx.x;
  const int lane = tid & 63, wv = tid >> 6;
  const int l15 = lane & 15, l4 = lane >> 4;
  const short* whh_d = whh + (long)dir * (4 * H) * KPAD;
  const int xoff = dir * 4 * H;
  const int ooff = dir * H;

  int u[NGW];
#pragma unroll
  for (int j = 0; j < NGW; ++j) {
    int g = wv + 4 * j; if (g > NG - 1) g = NG - 1;
    u[j] = g * 16 + l15;
  }

  { // zero LDS (K-pad columns must stay zero forever)
    short* hf = &hbuf[0][0][0];
    for (int i = tid; i < 2 * 16 * HP; i += 256) hf[i] = 0;
  }

  short8v bw[NGW][4][NK];
#pragma unroll
  for (int j = 0; j < NGW; ++j)
#pragma unroll
    for (int q = 0; q < 4; ++q)
#pragma unroll
      for (int kk = 0; kk < NK; ++kk) {
        bw[j][q][kk] = *(const short8v*)(whh_d + (long)(q * H + u[j]) * KPAD + kk * 32 + l4 * 8);
        pinv(bw[j][q][kk]);
      }

  float cst[NGW][4];
#pragma unroll
  for (int j = 0; j < NGW; ++j)
#pragma unroll
    for (int r = 0; r < 4; ++r) cst[j][r] = 0.0f;

  const int te0 = dir ? 511 : 0;
  short4v xc[NGW][4], xn[NGW][4];
#pragma unroll
  for (int j = 0; j < NGW; ++j)
#pragma unroll
    for (int r = 0; r < 4; ++r)
      xc[j][r] = *(const short4v*)(xg + ((long)(b0 + l4 * 4 + r) * 512 + te0) * ldxg + xoff + u[j] * 4);

  asm volatile("s_waitcnt lgkmcnt(0)" ::: "memory");
  __builtin_amdgcn_s_barrier();
  asm volatile("" ::: "memory");

  for (int t = 0; t < 512; ++t) {
    const int te = dir ? (511 - t) : t;
    const int cur = t & 1;

    float4v A[NGW][4];
#pragma unroll
    for (int j = 0; j < NGW; ++j)
#pragma unroll
      for (int q = 0; q < 4; ++q) A[j][q] = float4v{0, 0, 0, 0};

    if (t > 0) {
      short8v a[NK];
#pragma unroll
      for (int kk = 0; kk < NK; ++kk)
        a[kk] = *(const short8v*)&hbuf[cur ^ 1][l15][kk * 32 + l4 * 8];
#pragma unroll
      for (int j = 0; j < NGW; ++j)
#pragma unroll
        for (int kk = 0; kk < NK; ++kk) {
          A[j][0] = __builtin_amdgcn_mfma_f32_16x16x32_bf16(a[kk], bw[j][0][kk], A[j][0], 0, 0, 0);
          A[j][1] = __builtin_amdgcn_mfma_f32_16x16x32_bf16(a[kk], bw[j][1][kk], A[j][1], 0, 0, 0);
          A[j][2] = __builtin_amdgcn_mfma_f32_16x16x32_bf16(a[kk], bw[j][2][kk], A[j][2], 0, 0, 0);
          A[j][3] = __builtin_amdgcn_mfma_f32_16x16x32_bf16(a[kk], bw[j][3][kk], A[j][3], 0, 0, 0);
        }
    }

    if (t < 511) {
      const int ten = dir ? (te - 1) : (te + 1);
#pragma unroll
      for (int j = 0; j < NGW; ++j)
#pragma unroll
        for (int r = 0; r < 4; ++r)
          xn[j][r] = *(const short4v*)(xg + ((long)(b0 + l4 * 4 + r) * 512 + ten) * ldxg + xoff + u[j] * 4);
    }

#pragma unroll
    for (int j = 0; j < NGW; ++j)
#pragma unroll
      for (int r = 0; r < 4; ++r) {
        const long b_ = b0 + l4 * 4 + r;
        const long orow = (b_ * 512 + te) * ldo;
        float gi_ = A[j][0][r] + bf2f(xc[j][r][0]);
        float gf_ = A[j][1][r] + bf2f(xc[j][r][1]);
        float gg_ = A[j][2][r] + bf2f(xc[j][r][2]);
        float go_ = A[j][3][r] + bf2f(xc[j][r][3]);
        float iv = hsigf(gi_), fv = hsigf(gf_), gv = tanhf_fast(gg_), ov = hsigf(go_);
        float cn = fv * cst[j][r] + iv * gv;
        cst[j][r] = cn;
        short hb = f2bf(ov * tanhf_fast(cn));
        hbuf[cur][l4 * 4 + r][u[j]] = hb;   // duplicates write identical bytes
        out[orow + ooff + u[j]] = hb;
      }

#pragma unroll
    for (int j = 0; j < NGW; ++j)
#pragma unroll
      for (int r = 0; r < 4; ++r) xc[j][r] = xn[j][r];

    asm volatile("s_waitcnt lgkmcnt(0)" ::: "memory");
    __builtin_amdgcn_s_barrier();
    asm volatile("" ::: "memory");
    __builtin_amdgcn_sched_barrier(0);
  }
}

// ---------------------------------------------------------------------------
// dense + softmax
// ---------------------------------------------------------------------------
__global__ __launch_bounds__(256)
void dense_sm(const short* __restrict__ h, const float* __restrict__ w,
              const float* __restrict__ b, float* __restrict__ out) {
  __shared__ float wl[28 * 192];
  for (int i = threadIdx.x; i < 28 * 192; i += 256) wl[i] = w[i];
  __syncthreads();
  long m = (long)blockIdx.x * 256 + threadIdx.x;
  const short* hr = h + m * 192;
  float acc[28];
#pragma unroll
  for (int o = 0; o < 28; ++o) acc[o] = b[o];
  for (int cch = 0; cch < 24; ++cch) {
    short8v hv = *(const short8v*)(hr + cch * 8);
    float hf[8];
#pragma unroll
    for (int j = 0; j < 8; ++j) hf[j] = bf2f(hv[j]);
#pragma unroll
    for (int o = 0; o < 28; ++o) {
      const float* wp = &wl[o * 192 + cch * 8];
#pragma unroll
      for (int j = 0; j < 8; ++j) acc[o] = fmaf(hf[j], wp[j], acc[o]);
    }
  }
  float mx = acc[0];
#pragma unroll
  for (int o = 1; o < 28; ++o) mx = fmaxf(mx, acc[o]);
  float s = 0.0f;
#pragma unroll
  for (int o = 0; o < 28; ++o) { float e = __expf(acc[o] - mx); acc[o] = e; s += e; }
  float r = __fdividef(1.0f, s);
#pragma unroll
  for (int o = 0; o < 28; ++o) out[m * 28 + o] = acc[o] * r;
}

// ---------------------------------------------------------------------------
extern "C" void kernel_launch(void* const* d_in, const int* in_sizes, int n_in,
                              void* d_out, int out_size, void* d_ws, size_t ws_size,
                              hipStream_t stream) {
  const int*   x     = (const int*)d_in[0];
  const float* emb   = (const float*)d_in[1];
  const float* wih0f = (const float*)d_in[2];
  const float* whh0f = (const float*)d_in[3];
  const float* b0f   = (const float*)d_in[4];
  const float* wih0b = (const float*)d_in[5];
  const float* whh0b = (const float*)d_in[6];
  const float* b0b   = (const float*)d_in[7];
  const float* wih1f = (const float*)d_in[8];
  const float* whh1f = (const float*)d_in[9];
  const float* b1f   = (const float*)d_in[10];
  const float* wih1b = (const float*)d_in[11];
  const float* whh1b = (const float*)d_in[12];
  const float* b1b   = (const float*)d_in[13];
  const float* wih2f = (const float*)d_in[14];
  const float* whh2f = (const float*)d_in[15];
  const float* b2f   = (const float*)d_in[16];
  const float* wih2b = (const float*)d_in[17];
  const float* whh2b = (const float*)d_in[18];
  const float* b2b   = (const float*)d_in[19];
  const float* gamma = (const float*)d_in[20];
  const float* beta  = (const float*)d_in[21];
  const float* mean  = (const float*)d_in[22];
  const float* var   = (const float*)d_in[23];
  const float* dw    = (const float*)d_in[24];
  const float* db    = (const float*)d_in[25];

  char* ws = (char*)d_ws;
  size_t off = 0;
  auto alloc = [&](size_t bytes) -> void* {
    void* p = (void*)(ws + off);
    off += (bytes + 255) & ~(size_t)255;
    return p;
  };
  short* A0   = (short*)alloc(32768L * 288 * 2);
  short* XG   = (short*)alloc(32768L * 2304 * 2);
  short* OUT0 = (short*)alloc(32768L * 576 * 2);
  short* OUT1 = (short*)alloc(32768L * 288 * 2);
  short* OUT2 = (short*)alloc(32768L * 192 * 2);
  short* WG0  = (short*)alloc(2304L * 288 * 2);
  short* WG1  = (short*)alloc(1152L * 576 * 2);
  short* WG2  = (short*)alloc(768L * 288 * 2);
  short* WHH0 = (short*)alloc(2304L * 288 * 2);
  short* WHH1 = (short*)alloc(1152L * 160 * 2);
  short* WHH2 = (short*)alloc(768L * 96 * 2);
  float* B0   = (float*)alloc(2304 * 4);
  float* B1   = (float*)alloc(1152 * 4);
  float* B2   = (float*)alloc(768 * 4);
  int* FL     = (int*)alloc(2 * 512 * 32 * 4);
  if (off > ws_size) return;

  hipMemsetAsync(FL, 0, 2 * 512 * 32 * 4, stream);

  prep_misc<<<dim3(7068), dim3(256), 0, stream>>>(
      wih0f, wih0b, whh0f, whh0b, wih2f, wih2b, whh2f, whh2b, whh1f, whh1b,
      b0f, b0b, b2f, b2b, WG0, WG2, WHH0, WHH1, WHH2, B0, B2);
  prep_bn<<<dim3(1152), dim3(64), 0, stream>>>(
      wih1f, wih1b, b1f, b1b, gamma, beta, mean, var, WG1, B1);
  embed_k<<<dim3(2048), dim3(256), 0, stream>>>(x, emb, A0);

  // Layer 0 (cross-WG, LLC handshake)
  gemm_xg<<<dim3(256 * 18), dim3(256), 0, stream>>>(A0, WG0, B0, XG, 32768, 2304, 288, 1152, 288);
  hipLaunchKernelGGL(HIP_KERNEL_NAME(lstm_recX<288, 9, 18>), dim3(36), dim3(256), 0, stream,
                     XG, 2304, WHH0, OUT0, 576, FL);
  // Layer 1 (BN folded; fully WG-local)
  gemm_xg<<<dim3(256 * 9), dim3(256), 0, stream>>>(OUT0, WG1, B1, XG, 32768, 1152, 576, 576, 144);
  hipLaunchKernelGGL(HIP_KERNEL_NAME(lstm_loc<144, 5, 9, 3>), dim3(8), dim3(256), 0, stream,
                     XG, 1152, WHH1, OUT1, 288);
  // Layer 2 (fully WG-local)
  gemm_xg<<<dim3(256 * 6), dim3(256), 0, stream>>>(OUT1, WG2, B2, XG, 32768, 768, 288, 384, 96);
  hipLaunchKernelGGL(HIP_KERNEL_NAME(lstm_loc<96, 3, 6, 2>), dim3(8), dim3(256), 0, stream,
                     XG, 768, WHH2, OUT2, 192);
  // Dense + softmax
  dense_sm<<<dim3(128), dim3(256), 0, stream>>>(OUT2, dw, db, (float*)d_out);
}

// Round 7
// 3865.904 us; speedup vs baseline: 1.0336x; 1.0336x over previous
//
#include <hip/hip_runtime.h>
#include <stdint.h>

typedef __attribute__((ext_vector_type(8))) short short8v;
typedef __attribute__((ext_vector_type(4))) short short4v;
typedef __attribute__((ext_vector_type(4))) float float4v;

__device__ __forceinline__ float bf2f(short u) {
  union { unsigned int i; float f; } v;
  v.i = ((unsigned int)(unsigned short)u) << 16;
  return v.f;
}
__device__ __forceinline__ short f2bf(float f) {
  union { float f; unsigned int i; } v; v.f = f;
  unsigned int x = v.i;
  unsigned int r = (x + 0x7fffu + ((x >> 16) & 1u)) >> 16;
  return (short)r;
}
__device__ __forceinline__ float hsigf(float x) {
  return fminf(fmaxf(fmaf(x, 0.2f, 0.5f), 0.0f), 1.0f);
}
__device__ __forceinline__ float tanhf_fast(float x) {
  float e = __expf(2.0f * x);
  return 1.0f - __fdividef(2.0f, e + 1.0f);
}
__device__ __forceinline__ void gload_lds16(const void* g, void* l) {
  __builtin_amdgcn_global_load_lds((const __attribute__((address_space(1))) void*)g,
                                   (__attribute__((address_space(3))) void*)l, 16, 0, 0);
}
// Device-coherent 16B load: bypass the XCD-private L2 (sc0 sc1), coherent at LLC.
__device__ __forceinline__ short8v gload16_cc(const short* p) {
  short8v r;
  asm volatile("global_load_dwordx4 %0, %1, off sc0 sc1" : "=v"(r) : "v"(p));
  return r;
}
// Pin a weight fragment into AGPRs (forces v_accvgpr_write once; AGPR class).
__device__ __forceinline__ void pina(short8v& v) { asm volatile("" : "+a"(v)); }
// MFMA with B operand REQUIRED in AGPRs (gfx950 MFMA reads B from AGPR
// directly). asm-volatile: cannot be hoisted past handwritten s_waitcnt.
__device__ __forceinline__ void mfma_bA(float4v& d, short8v a, short8v b) {
  asm volatile("v_mfma_f32_16x16x32_bf16 %0, %1, %2, %0"
               : "+v"(d) : "v"(a), "a"(b));
}

// ---------------------------------------------------------------------------
// prep_misc: convert weights to bf16 work buffers (flat copies; WHH1 K-padded)
// ---------------------------------------------------------------------------
__global__ __launch_bounds__(256)
void prep_misc(const float* __restrict__ wih0f, const float* __restrict__ wih0b,
               const float* __restrict__ whh0f, const float* __restrict__ whh0b,
               const float* __restrict__ wih2f, const float* __restrict__ wih2b,
               const float* __restrict__ whh2f, const float* __restrict__ whh2b,
               const float* __restrict__ whh1f, const float* __restrict__ whh1b,
               const float* __restrict__ b0f, const float* __restrict__ b0b,
               const float* __restrict__ b2f, const float* __restrict__ b2b,
               short* __restrict__ WG0, short* __restrict__ WG2,
               short* __restrict__ WHH0, short* __restrict__ WHH1, short* __restrict__ WHH2,
               float* __restrict__ B0, float* __restrict__ B2) {
  int i = blockIdx.x * 256 + threadIdx.x;
  if (i < 663552) { WG0[i] = f2bf(i < 331776 ? wih0f[i] : wih0b[i - 331776]); return; }
  i -= 663552;
  if (i < 221184) { WG2[i] = f2bf(i < 110592 ? wih2f[i] : wih2b[i - 110592]); return; }
  i -= 221184;
  if (i < 663552) { WHH0[i] = f2bf(i < 331776 ? whh0f[i] : whh0b[i - 331776]); return; }
  i -= 663552;
  if (i < 184320) {
    int n = i / 160, k = i - n * 160;
    float v = 0.0f;
    if (k < 144) v = (n < 576) ? whh1f[n * 144 + k] : whh1b[(n - 576) * 144 + k];
    WHH1[i] = f2bf(v); return;
  }
  i -= 184320;
  if (i < 73728) { WHH2[i] = f2bf(i < 36864 ? whh2f[i] : whh2b[i - 36864]); return; }
  i -= 73728;
  if (i < 2304) { B0[i] = (i < 1152) ? b0f[i] : b0b[i - 1152]; return; }
  i -= 2304;
  if (i < 768) { B2[i] = (i < 384) ? b2f[i] : b2b[i - 384]; return; }
}

// ---------------------------------------------------------------------------
// prep_bn: fold BatchNorm into layer-1 input weights/bias
// ---------------------------------------------------------------------------
__global__ __launch_bounds__(64)
void prep_bn(const float* __restrict__ w1f, const float* __restrict__ w1b,
             const float* __restrict__ bf1, const float* __restrict__ bb1,
             const float* __restrict__ gamma, const float* __restrict__ beta,
             const float* __restrict__ mean, const float* __restrict__ var,
             short* __restrict__ WG1, float* __restrict__ B1) {
  int n = blockIdx.x;
  int lane = threadIdx.x;
  const float* wrow = (n < 576) ? (w1f + (long)n * 576) : (w1b + (long)(n - 576) * 576);
  float bsrc = (n < 576) ? bf1[n] : bb1[n - 576];
  float part = 0.0f;
  for (int k = lane; k < 576; k += 64) {
    float sc = gamma[k] * rsqrtf(var[k] + 1e-3f);
    float off = beta[k] - mean[k] * sc;
    float w = wrow[k];
    WG1[(long)n * 576 + k] = f2bf(w * sc);
    part += w * off;
  }
#pragma unroll
  for (int m = 32; m >= 1; m >>= 1) part += __shfl_xor(part, m, 64);
  if (lane == 0) B1[n] = bsrc + part;
}

// ---------------------------------------------------------------------------
// embed
// ---------------------------------------------------------------------------
__global__ __launch_bounds__(256)
void embed_k(const int* __restrict__ x, const float* __restrict__ emb, short* __restrict__ A0) {
  int p0 = blockIdx.x * 16;
  for (int j = threadIdx.x; j < 16 * 72; j += 256) {
    int p = p0 + j / 72;
    int cc = j - (j / 72) * 72;
    int idx = x[p];
    float4v v = *(const float4v*)(emb + (long)idx * 288 + cc * 4);
    short4v s;
    s[0] = f2bf(v[0]); s[1] = f2bf(v[1]); s[2] = f2bf(v[2]); s[3] = f2bf(v[3]);
    *(short4v*)(A0 + (long)p * 288 + cc * 4) = s;
  }
}

// ---------------------------------------------------------------------------
// gemm_xg (unchanged)
// ---------------------------------------------------------------------------
__global__ __launch_bounds__(256)
void gemm_xg(const short* __restrict__ A, const short* __restrict__ W,
             const float* __restrict__ bias, short* __restrict__ C,
             int M, int N, int K, int H4, int H) {
  __shared__ short As[128 * 32];
  __shared__ short Bs[128 * 32];
  const int nbn = N >> 7;
  const int bm = blockIdx.x / nbn;
  const int bn = blockIdx.x - bm * nbn;
  const long m0 = (long)bm << 7;
  const int n0 = bn << 7;
  const int tid = threadIdx.x;
  const int lane = tid & 63, wv = tid >> 6;
  const int wr = wv >> 1, wc = wv & 1;
  const int l15 = lane & 15, l4 = lane >> 4;

  float4v acc[4][4];
#pragma unroll
  for (int j = 0; j < 4; ++j) {
    float bvj = bias[n0 + wc * 64 + j * 16 + l15];
#pragma unroll
    for (int i = 0; i < 4; ++i) acc[i][j] = float4v{bvj, bvj, bvj, bvj};
  }

  for (int kt = 0; kt < K; kt += 32) {
#pragma unroll
    for (int c = 0; c < 2; ++c) {
      int ci = wv * 128 + c * 64 + lane;
      int row = ci >> 2, slot = ci & 3;
      int k8 = slot ^ (row & 3);
      gload_lds16(A + (m0 + row) * K + kt + k8 * 8, &As[ci * 8]);
      gload_lds16(W + (long)(n0 + row) * K + kt + k8 * 8, &Bs[ci * 8]);
    }
    __syncthreads();
    short8v af[4], bf[4];
#pragma unroll
    for (int i = 0; i < 4; ++i) {
      int row = wr * 64 + i * 16 + l15;
      af[i] = *(const short8v*)&As[row * 32 + ((l4 ^ (row & 3)) * 8)];
    }
#pragma unroll
    for (int j = 0; j < 4; ++j) {
      int row = wc * 64 + j * 16 + l15;
      bf[j] = *(const short8v*)&Bs[row * 32 + ((l4 ^ (row & 3)) * 8)];
    }
#pragma unroll
    for (int i = 0; i < 4; ++i)
#pragma unroll
      for (int j = 0; j < 4; ++j)
        acc[i][j] = __builtin_amdgcn_mfma_f32_16x16x32_bf16(af[i], bf[j], acc[i][j], 0, 0, 0);
    __syncthreads();
  }

#pragma unroll
  for (int j = 0; j < 4; ++j) {
    int n = n0 + wc * 64 + j * 16 + l15;
    int dir = n / H4;
    int rem = n - dir * H4;
    int q = rem / H;
    int u = rem - q * H;
    long np = (long)dir * H4 + u * 4 + q;
#pragma unroll
    for (int i = 0; i < 4; ++i) {
#pragma unroll
      for (int r = 0; r < 4; ++r) {
        long row = m0 + wr * 64 + i * 16 + l4 * 4 + r;
        C[row * N + np] = f2bf(acc[i][j][r]);
      }
    }
  }
}

// ---------------------------------------------------------------------------
// lstm_recX (L0): cross-WG unit-split recurrence. Weights live in AGPRs
// (pina + asm MFMA with "a" B-operand). h exchanged via LLC (agent atomic
// stores / sc0sc1 loads); per-WG flag handshake.
// ---------------------------------------------------------------------------
template<int H, int NK, int NU>
__global__ __launch_bounds__(256)
__attribute__((amdgpu_waves_per_eu(1, 1)))
void lstm_recX(const short* __restrict__ xg, int ldxg,
               const short* __restrict__ whh,
               short* __restrict__ out, int ldo,
               int* __restrict__ fl) {
  constexpr int KPAD = NK * 32;
  const int dir = blockIdx.x & 1;
  const int us = blockIdx.x >> 1;
  const int tid = threadIdx.x;
  const int lane = tid & 63;
  const int mt = tid >> 6;
  const int l15 = lane & 15, l4 = lane >> 4;
  int* fl_d = fl + dir * 512 * 32;
  const short* whh_d = whh + (long)dir * (4 * H) * KPAD;
  const int xoff = dir * 4 * H;
  const int ooff = dir * H;
  const int u = us * 16 + l15;

  // weights -> AGPRs (one-time v_accvgpr_write; resident for the whole loop)
  short8v bw[4][NK];
#pragma unroll
  for (int q = 0; q < 4; ++q)
#pragma unroll
    for (int kk = 0; kk < NK; ++kk) {
      bw[q][kk] = *(const short8v*)(whh_d + (long)(q * H + u) * KPAD + kk * 32 + l4 * 8);
      pina(bw[q][kk]);
    }

  float cst[4] = {0.0f, 0.0f, 0.0f, 0.0f};
  const int flidx = (lane < NU) ? lane : 0;

  for (int t = 0; t < 512; ++t) {
    const int te = dir ? (511 - t) : t;

    short4v x4[4];
#pragma unroll
    for (int r = 0; r < 4; ++r) {
      const long b_ = mt * 16 + l4 * 4 + r;
      x4[r] = *(const short4v*)(xg + (b_ * 512 + te) * ldxg + xoff + u * 4);
    }

    float4v a0 = {0, 0, 0, 0}, a1 = {0, 0, 0, 0}, a2 = {0, 0, 0, 0}, a3 = {0, 0, 0, 0};
    if (t > 0) {
      const int tp = dir ? (te + 1) : (te - 1);
      int* fb = fl_d + (t - 1) * 32 + flidx;
      while (!__all(__hip_atomic_load(fb, __ATOMIC_RELAXED, __HIP_MEMORY_SCOPE_AGENT) != 0)) {}
      __builtin_amdgcn_sched_barrier(0);
      const short* hbase = out + ((long)(mt * 16 + l15) * 512 + tp) * ldo + ooff + l4 * 8;
      short8v a[NK];
#pragma unroll
      for (int kk = 0; kk < NK; ++kk) a[kk] = gload16_cc(hbase + kk * 32);
      asm volatile("s_waitcnt vmcnt(0)" ::: "memory");
      __builtin_amdgcn_sched_barrier(0);
      asm volatile("s_nop 1" :::);
#pragma unroll
      for (int kk = 0; kk < NK; ++kk) {
        mfma_bA(a0, a[kk], bw[0][kk]);
        mfma_bA(a1, a[kk], bw[1][kk]);
        mfma_bA(a2, a[kk], bw[2][kk]);
        mfma_bA(a3, a[kk], bw[3][kk]);
      }
      asm volatile("s_nop 7\n\ts_nop 7" :::);  // MFMA D -> VALU read hazard
    }

#pragma unroll
    for (int r = 0; r < 4; ++r) {
      const long b_ = mt * 16 + l4 * 4 + r;
      const long orow = (b_ * 512 + te) * ldo;
      float gi_ = a0[r] + bf2f(x4[r][0]);
      float gf_ = a1[r] + bf2f(x4[r][1]);
      float gg_ = a2[r] + bf2f(x4[r][2]);
      float go_ = a3[r] + bf2f(x4[r][3]);
      float iv = hsigf(gi_), fv = hsigf(gf_), gv = tanhf_fast(gg_), ov = hsigf(go_);
      float cn = fv * cst[r] + iv * gv;
      cst[r] = cn;
      __hip_atomic_store(out + orow + ooff + u, f2bf(ov * tanhf_fast(cn)),
                         __ATOMIC_RELAXED, __HIP_MEMORY_SCOPE_AGENT);
    }

    asm volatile("s_waitcnt vmcnt(0)" ::: "memory");
    __syncthreads();  // all 4 waves drained before this WG's flag
    if (tid == 0)
      __hip_atomic_store(fl_d + t * 32 + us, 1, __ATOMIC_RELAXED, __HIP_MEMORY_SCOPE_AGENT);
  }
}

// ---------------------------------------------------------------------------
// lstm_loc (L1/L2): fully WG-local recurrence. WG = (dir, 16-batch-group);
// grid = 8. Weights in AGPRs (pina + asm MFMA). h in LDS, one raw barrier
// per step. Zero cross-WG communication.
// ---------------------------------------------------------------------------
template<int H, int NK, int NG, int NGW>
__global__ __launch_bounds__(256)
__attribute__((amdgpu_waves_per_eu(1, 1)))
void lstm_loc(const short* __restrict__ xg, int ldxg,
              const short* __restrict__ whh,
              short* __restrict__ out, int ldo) {
  constexpr int KPAD = NK * 32;
  constexpr int HP = KPAD + 8;
  __shared__ __align__(16) short hbuf[2][16][HP];
  const int dir = blockIdx.x & 1;
  const int bg = blockIdx.x >> 1;
  const int b0 = bg * 16;
  const int tid = threadIdx.x;
  const int lane = tid & 63, wv = tid >> 6;
  const int l15 = lane & 15, l4 = lane >> 4;
  const short* whh_d = whh + (long)dir * (4 * H) * KPAD;
  const int xoff = dir * 4 * H;
  const int ooff = dir * H;

  int u[NGW];
#pragma unroll
  for (int j = 0; j < NGW; ++j) {
    int g = wv + 4 * j; if (g > NG - 1) g = NG - 1;
    u[j] = g * 16 + l15;
  }

  { // zero LDS (K-pad columns must stay zero forever)
    short* hf = &hbuf[0][0][0];
    for (int i = tid; i < 2 * 16 * HP; i += 256) hf[i] = 0;
  }

  short8v bw[NGW][4][NK];
#pragma unroll
  for (int j = 0; j < NGW; ++j)
#pragma unroll
    for (int q = 0; q < 4; ++q)
#pragma unroll
      for (int kk = 0; kk < NK; ++kk) {
        bw[j][q][kk] = *(const short8v*)(whh_d + (long)(q * H + u[j]) * KPAD + kk * 32 + l4 * 8);
        pina(bw[j][q][kk]);
      }

  float cst[NGW][4];
#pragma unroll
  for (int j = 0; j < NGW; ++j)
#pragma unroll
    for (int r = 0; r < 4; ++r) cst[j][r] = 0.0f;

  const int te0 = dir ? 511 : 0;
  short4v xc[NGW][4], xn[NGW][4];
#pragma unroll
  for (int j = 0; j < NGW; ++j)
#pragma unroll
    for (int r = 0; r < 4; ++r)
      xc[j][r] = *(const short4v*)(xg + ((long)(b0 + l4 * 4 + r) * 512 + te0) * ldxg + xoff + u[j] * 4);

  asm volatile("s_waitcnt lgkmcnt(0)" ::: "memory");
  __builtin_amdgcn_s_barrier();
  asm volatile("" ::: "memory");

  for (int t = 0; t < 512; ++t) {
    const int te = dir ? (511 - t) : t;
    const int cur = t & 1;

    float4v A[NGW][4];
#pragma unroll
    for (int j = 0; j < NGW; ++j)
#pragma unroll
      for (int q = 0; q < 4; ++q) A[j][q] = float4v{0, 0, 0, 0};

    if (t > 0) {
      short8v a[NK];
#pragma unroll
      for (int kk = 0; kk < NK; ++kk)
        a[kk] = *(const short8v*)&hbuf[cur ^ 1][l15][kk * 32 + l4 * 8];
      asm volatile("s_nop 1" :::);
#pragma unroll
      for (int j = 0; j < NGW; ++j)
#pragma unroll
        for (int kk = 0; kk < NK; ++kk) {
          mfma_bA(A[j][0], a[kk], bw[j][0][kk]);
          mfma_bA(A[j][1], a[kk], bw[j][1][kk]);
          mfma_bA(A[j][2], a[kk], bw[j][2][kk]);
          mfma_bA(A[j][3], a[kk], bw[j][3][kk]);
        }
      asm volatile("s_nop 7\n\ts_nop 7" :::);  // MFMA D -> VALU read hazard
    }

    if (t < 511) {
      const int ten = dir ? (te - 1) : (te + 1);
#pragma unroll
      for (int j = 0; j < NGW; ++j)
#pragma unroll
        for (int r = 0; r < 4; ++r)
          xn[j][r] = *(const short4v*)(xg + ((long)(b0 + l4 * 4 + r) * 512 + ten) * ldxg + xoff + u[j] * 4);
    }

#pragma unroll
    for (int j = 0; j < NGW; ++j)
#pragma unroll
      for (int r = 0; r < 4; ++r) {
        const long b_ = b0 + l4 * 4 + r;
        const long orow = (b_ * 512 + te) * ldo;
        float gi_ = A[j][0][r] + bf2f(xc[j][r][0]);
        float gf_ = A[j][1][r] + bf2f(xc[j][r][1]);
        float gg_ = A[j][2][r] + bf2f(xc[j][r][2]);
        float go_ = A[j][3][r] + bf2f(xc[j][r][3]);
        float iv = hsigf(gi_), fv = hsigf(gf_), gv = tanhf_fast(gg_), ov = hsigf(go_);
        float cn = fv * cst[j][r] + iv * gv;
        cst[j][r] = cn;
        short hb = f2bf(ov * tanhf_fast(cn));
        hbuf[cur][l4 * 4 + r][u[j]] = hb;   // duplicates write identical bytes
        out[orow + ooff + u[j]] = hb;
      }

#pragma unroll
    for (int j = 0; j < NGW; ++j)
#pragma unroll
      for (int r = 0; r < 4; ++r) xc[j][r] = xn[j][r];

    asm volatile("s_waitcnt lgkmcnt(0)" ::: "memory");
    __builtin_amdgcn_s_barrier();
    asm volatile("" ::: "memory");
    __builtin_amdgcn_sched_barrier(0);
  }
}

// ---------------------------------------------------------------------------
// dense + softmax
// ---------------------------------------------------------------------------
__global__ __launch_bounds__(256)
void dense_sm(const short* __restrict__ h, const float* __restrict__ w,
              const float* __restrict__ b, float* __restrict__ out) {
  __shared__ float wl[28 * 192];
  for (int i = threadIdx.x; i < 28 * 192; i += 256) wl[i] = w[i];
  __syncthreads();
  long m = (long)blockIdx.x * 256 + threadIdx.x;
  const short* hr = h + m * 192;
  float acc[28];
#pragma unroll
  for (int o = 0; o < 28; ++o) acc[o] = b[o];
  for (int cch = 0; cch < 24; ++cch) {
    short8v hv = *(const short8v*)(hr + cch * 8);
    float hf[8];
#pragma unroll
    for (int j = 0; j < 8; ++j) hf[j] = bf2f(hv[j]);
#pragma unroll
    for (int o = 0; o < 28; ++o) {
      const float* wp = &wl[o * 192 + cch * 8];
#pragma unroll
      for (int j = 0; j < 8; ++j) acc[o] = fmaf(hf[j], wp[j], acc[o]);
    }
  }
  float mx = acc[0];
#pragma unroll
  for (int o = 1; o < 28; ++o) mx = fmaxf(mx, acc[o]);
  float s = 0.0f;
#pragma unroll
  for (int o = 0; o < 28; ++o) { float e = __expf(acc[o] - mx); acc[o] = e; s += e; }
  float r = __fdividef(1.0f, s);
#pragma unroll
  for (int o = 0; o < 28; ++o) out[m * 28 + o] = acc[o] * r;
}

// ---------------------------------------------------------------------------
extern "C" void kernel_launch(void* const* d_in, const int* in_sizes, int n_in,
                              void* d_out, int out_size, void* d_ws, size_t ws_size,
                              hipStream_t stream) {
  const int*   x     = (const int*)d_in[0];
  const float* emb   = (const float*)d_in[1];
  const float* wih0f = (const float*)d_in[2];
  const float* whh0f = (const float*)d_in[3];
  const float* b0f   = (const float*)d_in[4];
  const float* wih0b = (const float*)d_in[5];
  const float* whh0b = (const float*)d_in[6];
  const float* b0b   = (const float*)d_in[7];
  const float* wih1f = (const float*)d_in[8];
  const float* whh1f = (const float*)d_in[9];
  const float* b1f   = (const float*)d_in[10];
  const float* wih1b = (const float*)d_in[11];
  const float* whh1b = (const float*)d_in[12];
  const float* b1b   = (const float*)d_in[13];
  const float* wih2f = (const float*)d_in[14];
  const float* whh2f = (const float*)d_in[15];
  const float* b2f   = (const float*)d_in[16];
  const float* wih2b = (const float*)d_in[17];
  const float* whh2b = (const float*)d_in[18];
  const float* b2b   = (const float*)d_in[19];
  const float* gamma = (const float*)d_in[20];
  const float* beta  = (const float*)d_in[21];
  const float* mean  = (const float*)d_in[22];
  const float* var   = (const float*)d_in[23];
  const float* dw    = (const float*)d_in[24];
  const float* db    = (const float*)d_in[25];

  char* ws = (char*)d_ws;
  size_t off = 0;
  auto alloc = [&](size_t bytes) -> void* {
    void* p = (void*)(ws + off);
    off += (bytes + 255) & ~(size_t)255;
    return p;
  };
  short* A0   = (short*)alloc(32768L * 288 * 2);
  short* XG   = (short*)alloc(32768L * 2304 * 2);
  short* OUT0 = (short*)alloc(32768L * 576 * 2);
  short* OUT1 = (short*)alloc(32768L * 288 * 2);
  short* OUT2 = (short*)alloc(32768L * 192 * 2);
  short* WG0  = (short*)alloc(2304L * 288 * 2);
  short* WG1  = (short*)alloc(1152L * 576 * 2);
  short* WG2  = (short*)alloc(768L * 288 * 2);
  short* WHH0 = (short*)alloc(2304L * 288 * 2);
  short* WHH1 = (short*)alloc(1152L * 160 * 2);
  short* WHH2 = (short*)alloc(768L * 96 * 2);
  float* B0   = (float*)alloc(2304 * 4);
  float* B1   = (float*)alloc(1152 * 4);
  float* B2   = (float*)alloc(768 * 4);
  int* FL     = (int*)alloc(2 * 512 * 32 * 4);
  if (off > ws_size) return;

  hipMemsetAsync(FL, 0, 2 * 512 * 32 * 4, stream);

  prep_misc<<<dim3(7068), dim3(256), 0, stream>>>(
      wih0f, wih0b, whh0f, whh0b, wih2f, wih2b, whh2f, whh2b, whh1f, whh1b,
      b0f, b0b, b2f, b2b, WG0, WG2, WHH0, WHH1, WHH2, B0, B2);
  prep_bn<<<dim3(1152), dim3(64), 0, stream>>>(
      wih1f, wih1b, b1f, b1b, gamma, beta, mean, var, WG1, B1);
  embed_k<<<dim3(2048), dim3(256), 0, stream>>>(x, emb, A0);

  // Layer 0 (cross-WG, LLC handshake)
  gemm_xg<<<dim3(256 * 18), dim3(256), 0, stream>>>(A0, WG0, B0, XG, 32768, 2304, 288, 1152, 288);
  hipLaunchKernelGGL(HIP_KERNEL_NAME(lstm_recX<288, 9, 18>), dim3(36), dim3(256), 0, stream,
                     XG, 2304, WHH0, OUT0, 576, FL);
  // Layer 1 (BN folded; fully WG-local)
  gemm_xg<<<dim3(256 * 9), dim3(256), 0, stream>>>(OUT0, WG1, B1, XG, 32768, 1152, 576, 576, 144);
  hipLaunchKernelGGL(HIP_KERNEL_NAME(lstm_loc<144, 5, 9, 3>), dim3(8), dim3(256), 0, stream,
                     XG, 1152, WHH1, OUT1, 288);
  // Layer 2 (fully WG-local)
  gemm_xg<<<dim3(256 * 6), dim3(256), 0, stream>>>(OUT1, WG2, B2, XG, 32768, 768, 288, 384, 96);
  hipLaunchKernelGGL(HIP_KERNEL_NAME(lstm_loc<96, 3, 6, 2>), dim3(8), dim3(256), 0, stream,
                     XG, 768, WHH2, OUT2, 192);
  // Dense + softmax
  dense_sm<<<dim3(128), dim3(256), 0, stream>>>(OUT2, dw, db, (float*)d_out);
}